// Round 8
// baseline (32.791 us; speedup 1.0000x reference)
//
#include <hip/hip_runtime.h>
#include <math.h>

namespace {
constexpr int   KMAX   = 12;
constexpr int   NLINE  = 313;                  // half-space (h,k) lines
constexpr int   NL25   = 25;                   // l = -12..12
constexpr int   NKV    = NLINE * NL25;         // 7825 (13 masked in stage2)
constexpr int   KDIM   = 4096;                 // particle dim (padded)
constexpr int   MROWS  = 640;                  // [Pr rows 0..319 | Pi rows 320..639]
constexpr int   NCOLS  = 64;                   // [Rr cols 0..31 | Ri cols 32..63]
constexpr int   NKS    = 8;                    // split-K factor
constexpr int   KCHUNK = KDIM / NKS;           // 512
constexpr int   S2_BLOCKS = (NKV + 255) / 256; // 31
constexpr float ALPHA_  = 0.34f;
constexpr float TWO_PI_ = 6.283185307179586f;

typedef __attribute__((ext_vector_type(4))) short    short4v;
typedef __attribute__((ext_vector_type(8))) _Float16 half8;
typedef __attribute__((ext_vector_type(4))) float    f32x4;
}

__device__ __forceinline__ void cofactors(const float* __restrict__ box,
                                          float C[3][3], float* det) {
  const float b00 = box[0], b01 = box[1], b02 = box[2];
  const float b10 = box[3], b11 = box[4], b12 = box[5];
  const float b20 = box[6], b21 = box[7], b22 = box[8];
  C[0][0] =  (b11 * b22 - b12 * b21);
  C[0][1] = -(b10 * b22 - b12 * b20);
  C[0][2] =  (b10 * b21 - b11 * b20);
  C[1][0] = -(b01 * b22 - b02 * b21);
  C[1][1] =  (b00 * b22 - b02 * b20);
  C[1][2] = -(b00 * b21 - b01 * b20);
  C[2][0] =  (b01 * b12 - b02 * b11);
  C[2][1] = -(b00 * b12 - b02 * b10);
  C[2][2] =  (b00 * b11 - b01 * b10);
  *det = b00 * C[0][0] + b01 * C[0][1] + b02 * C[0][2];
}

// Half-space lines: L<300: h=1..12 x k=-12..12; L=300..311: h=0,k=1..12; L=312: h=k=0.
__device__ __forceinline__ void line_hk(int L, int* h, int* k) {
  if (L < 300)      { *h = L / 25 + 1; *k = L % 25 - 12; }
  else if (L < 312) { *h = 0;          *k = L - 299;     }
  else              { *h = 0;          *k = 0;           }
}

// Build A (640 x 4096 fp16: q*cos / q*sin of line phase) and
//       Bt (64 x 4096 fp16: cos / sin of l*c), k-major rows. Zeroes pads + out.
__global__ __launch_bounds__(256) void build_ab(
    const float* __restrict__ coords, const float* __restrict__ box,
    const float* __restrict__ q, int N,
    _Float16* __restrict__ A2, _Float16* __restrict__ Bt,
    float* __restrict__ out)
{
  const int id = blockIdx.x * 256 + threadIdx.x;
  if (id == 0) out[0] = 0.0f;   // atomic target for stage2 (stream-ordered)

  float C[3][3], det;
  cofactors(box, C, &det);
  const float invdet = 1.0f / det;

  if (id < 320 * KDIM) {
    const int Ls = id >> 12;           // 0..319 (313 used)
    const int i  = id & (KDIM - 1);
    float pr = 0.f, pi_ = 0.f;
    if (Ls < NLINE && i < N) {
      int h, k; line_hk(Ls, &h, &k);
      const float x = coords[3 * i + 0];
      const float y = coords[3 * i + 1];
      const float z = coords[3 * i + 2];
      const float a = (x * C[0][0] + y * C[0][1] + z * C[0][2]) * invdet;
      const float b = (x * C[1][0] + y * C[1][1] + z * C[1][2]) * invdet;
      float t = fmaf((float)h, a, (float)k * b);   // revolutions
      float tf; asm("v_fract_f32 %0, %1" : "=v"(tf) : "v"(t));
      float s0, c0;
      asm("v_sin_f32 %0, %1" : "=v"(s0) : "v"(tf));
      asm("v_cos_f32 %0, %1" : "=v"(c0) : "v"(tf));
      const float qq = q[i];
      pr = qq * c0; pi_ = qq * s0;
    }
    A2[(size_t)Ls * KDIM + i]         = (_Float16)pr;
    A2[(size_t)(320 + Ls) * KDIM + i] = (_Float16)pi_;
  } else {
    const int j = id - 320 * KDIM;
    if (j < 32 * KDIM) {
      const int ls = j >> 12;          // 0..31 (25 used)
      const int i  = j & (KDIM - 1);
      float cr = 0.f, sr = 0.f;
      if (ls < NL25 && i < N) {
        const int l = ls - KMAX;
        const float x = coords[3 * i + 0];
        const float y = coords[3 * i + 1];
        const float z = coords[3 * i + 2];
        const float c = (x * C[2][0] + y * C[2][1] + z * C[2][2]) * invdet;
        float t = (float)l * c;
        float tf; asm("v_fract_f32 %0, %1" : "=v"(tf) : "v"(t));
        asm("v_sin_f32 %0, %1" : "=v"(sr) : "v"(tf));
        asm("v_cos_f32 %0, %1" : "=v"(cr) : "v"(tf));
      }
      Bt[(size_t)ls * KDIM + i]        = (_Float16)cr;
      Bt[(size_t)(32 + ls) * KDIM + i] = (_Float16)sr;
    }
  }
}

// C[640 x 64] = A2 x Bt^T via mfma_f32_16x16x32_f16, split-K by 8.
// A-frag: row = lane&15; B-frag: col = lane&15; both use the SAME per-lane
// k-map sigma(lane,e) = (e&3) + 4*(lane>>4) + 16*(e>>2)  (any consistent
// bijection cancels in the K-sum). C layout: col=lane&15, row=(lane>>4)*4+reg.
__global__ __launch_bounds__(256) void gemm_sf(
    const _Float16* __restrict__ A2, const _Float16* __restrict__ Bt,
    float* __restrict__ Cp)
{
  const int w    = (blockIdx.x * 256 + threadIdx.x) >> 6;  // 0..1279
  const int lane = threadIdx.x & 63;
  const int ks   = w & 7;        // split-K slice
  const int tile = w >> 3;       // 0..159
  const int mt   = tile >> 2;    // 0..39
  const int nt   = tile & 3;     // 0..3
  const int r = lane & 15, g = lane >> 4;

  const _Float16* arow = A2 + (size_t)(mt * 16 + r) * KDIM + ks * KCHUNK + g * 4;
  const _Float16* brow = Bt + (size_t)(nt * 16 + r) * KDIM + ks * KCHUNK + g * 4;

  f32x4 acc = {0.f, 0.f, 0.f, 0.f};
#pragma unroll
  for (int st = 0; st < KCHUNK / 32; ++st) {   // 16 K-steps of 32
    union { short4v s[2]; half8 h8; } ua, ub;
    ua.s[0] = *(const short4v*)(arow + st * 32);
    ua.s[1] = *(const short4v*)(arow + st * 32 + 16);
    ub.s[0] = *(const short4v*)(brow + st * 32);
    ub.s[1] = *(const short4v*)(brow + st * 32 + 16);
    acc = __builtin_amdgcn_mfma_f32_16x16x32_f16(ua.h8, ub.h8, acc, 0, 0, 0);
  }

  float* ctile = Cp + ((size_t)ks * MROWS + mt * 16 + g * 4) * NCOLS + nt * 16 + r;
#pragma unroll
  for (int j = 0; j < 4; ++j) ctile[(size_t)j * NCOLS] = acc[j];
}

// Per k-vec: sum split-K, combine complex blocks, weight by fac, reduce, atomic.
__global__ __launch_bounds__(256) void stage2(
    const float* __restrict__ Cp, const float* __restrict__ box,
    float* __restrict__ out)
{
  __shared__ float red[256];
  const int idx = blockIdx.x * 256 + threadIdx.x;
  float e = 0.f;
  if (idx < NKV) {
    const int L  = idx / NL25;
    const int ls = idx % NL25;
    const int l  = ls - KMAX;
    int h, k; line_hk(L, &h, &k);
    if (!(h == 0 && k == 0 && l <= 0)) {   // mask non-half-space entries
      float Sre = 0.f, Sim = 0.f;
      for (int s = 0; s < NKS; ++s) {
        const float* c0 = Cp + (size_t)s * MROWS * NCOLS;
        const float prr = c0[(size_t)L * NCOLS + ls];              // Pr.Rr
        const float pri = c0[(size_t)L * NCOLS + 32 + ls];         // Pr.Ri
        const float pir = c0[(size_t)(320 + L) * NCOLS + ls];      // Pi.Rr
        const float pii = c0[(size_t)(320 + L) * NCOLS + 32 + ls]; // Pi.Ri
        Sre += prr - pii;
        Sim += pri + pir;
      }
      float C[3][3], det;
      cofactors(box, C, &det);
      const float invdet = 1.0f / det;
      const float hf = (float)h, kf = (float)k, lf = (float)l;
      const float kx = (hf * C[0][0] + kf * C[1][0] + lf * C[2][0]) * invdet;
      const float ky = (hf * C[0][1] + kf * C[1][1] + lf * C[2][1]) * invdet;
      const float kz = (hf * C[0][2] + kf * C[1][2] + lf * C[2][2]) * invdet;
      const float k2 = TWO_PI_ * TWO_PI_ * (kx * kx + ky * ky + kz * kz);
      const float fac = __expf(-k2 / (4.0f * ALPHA_ * ALPHA_)) / k2;
      e = fac * fmaf(Sre, Sre, Sim * Sim);
    }
  }
  red[threadIdx.x] = e;
  __syncthreads();
  for (int s = 128; s > 0; s >>= 1) {
    if (threadIdx.x < s) red[threadIdx.x] += red[threadIdx.x + s];
    __syncthreads();
  }
  if (threadIdx.x == 0) {
    float C[3][3], det;
    cofactors(box, C, &det);
    // E = (2*pi/V)*full_sum = (4*pi/V)*half_sum
    const float scale = (4.0f * 3.14159265358979323846f) / fabsf(det);
    atomicAdd(out, scale * red[0]);
  }
}

extern "C" void kernel_launch(void* const* d_in, const int* in_sizes, int n_in,
                              void* d_out, int out_size, void* d_ws, size_t ws_size,
                              hipStream_t stream) {
  const float* coords = (const float*)d_in[0];
  const float* box    = (const float*)d_in[1];
  const float* q      = (const float*)d_in[2];
  float* out = (float*)d_out;
  const int N = in_sizes[2];

  // ws layout (7,077,888 B total):
  //   A2 @ 0        : 640*4096 fp16 = 5,242,880 B
  //   Bt @ 5242880  :  64*4096 fp16 =   524,288 B
  //   Cp @ 5767168  : 8*640*64 f32  = 1,310,720 B
  _Float16* A2 = (_Float16*)d_ws;
  _Float16* Bt = (_Float16*)((char*)d_ws + 5242880);
  float*    Cp = (float*)   ((char*)d_ws + 5767168);

  const int build_blocks = (352 * KDIM) / 256;   // 5632
  hipLaunchKernelGGL(build_ab, dim3(build_blocks), dim3(256), 0, stream,
                     coords, box, q, N, A2, Bt, out);
  hipLaunchKernelGGL(gemm_sf, dim3(320), dim3(256), 0, stream, A2, Bt, Cp);
  hipLaunchKernelGGL(stage2, dim3(S2_BLOCKS), dim3(256), 0, stream,
                     Cp, box, out);
}

// Round 9
// 22.148 us; speedup vs baseline: 1.4805x; 1.4805x over previous
//
#include <hip/hip_runtime.h>
#include <math.h>

namespace {
constexpr int   KMAX  = 12;
constexpr int   NLINE = 313;                   // half-space (h,k) lines
constexpr int   NL25  = 25;                    // l = -12..12
constexpr int   NKV   = NLINE * NL25;          // 7825 (13 masked in stage2)
constexpr int   KDIM  = 4096;                  // particle dim (padded)
constexpr int   NKS   = 32;                    // split-K (grid.y)
constexpr int   KC    = KDIM / NKS;            // 128 particles per block
constexpr int   MROWS = 640;                   // interleaved: row 2L=Pr, 2L+1=Pi
constexpr int   NCOLS = 64;                    // interleaved: col 2ls=Rr, 2ls+1=Ri
constexpr int   S2_BLOCKS = (NKV + 255) / 256; // 31
constexpr float ALPHA_  = 0.34f;
constexpr float TWO_PI_ = 6.283185307179586f;

typedef __attribute__((ext_vector_type(4))) _Float16 half4;
typedef __attribute__((ext_vector_type(8))) _Float16 half8;
typedef __attribute__((ext_vector_type(4))) float    f32x4;
}

__device__ __forceinline__ void cofactors(const float* __restrict__ box,
                                          float C[3][3], float* det) {
  const float b00 = box[0], b01 = box[1], b02 = box[2];
  const float b10 = box[3], b11 = box[4], b12 = box[5];
  const float b20 = box[6], b21 = box[7], b22 = box[8];
  C[0][0] =  (b11 * b22 - b12 * b21);
  C[0][1] = -(b10 * b22 - b12 * b20);
  C[0][2] =  (b10 * b21 - b11 * b20);
  C[1][0] = -(b01 * b22 - b02 * b21);
  C[1][1] =  (b00 * b22 - b02 * b20);
  C[1][2] = -(b00 * b21 - b01 * b20);
  C[2][0] =  (b01 * b12 - b02 * b11);
  C[2][1] = -(b00 * b12 - b02 * b10);
  C[2][2] =  (b00 * b11 - b01 * b10);
  *det = b00 * C[0][0] + b01 * C[0][1] + b02 * C[0][2];
}

// Half-space lines: L<300: h=1..12 x k=-12..12; L=300..311: h=0,k=1..12; L>=312: h=k=0.
__device__ __forceinline__ void line_hk(int L, int* h, int* k) {
  if (L < 300)      { *h = L / 25 + 1; *k = L % 25 - 12; }
  else if (L < 312) { *h = 0;          *k = L - 299;     }
  else              { *h = 0;          *k = 0;           }
}

// Fused: synthesize A/B tiles (fp16 phasors) directly in LDS, MFMA from LDS.
// Block = (mtg 0..9, ks 0..31): rows mtg*64..+63 (= L-pairs), particles ks*128..+127.
// LDS panel [tile][kt][row][k0]: frag load lane(r,g) reads [s*8+g(+4)][r][0..3] ->
// dense 512B per wave-load; same k-map sigma for A and B cancels in the K-sum.
__global__ __launch_bounds__(256) void build_gemm(
    const float* __restrict__ coords, const float* __restrict__ box,
    const float* __restrict__ q, int N,
    float* __restrict__ Cp, float* __restrict__ out)
{
  __shared__ _Float16 Al[4][32][16][4];   // 16 KiB: rows (2L|2L+1) of 4 m-tiles
  __shared__ _Float16 Bl[4][32][16][4];   // 16 KiB: cols (2ls|2ls+1) of 4 n-tiles

  const int mtg = blockIdx.x;   // 0..9
  const int ks  = blockIdx.y;   // 0..31
  if (mtg == 0 && ks == 0 && threadIdx.x == 0) out[0] = 0.0f;

  float C[3][3], det;
  cofactors(box, C, &det);
  const float invdet = 1.0f / det;

  // ---- build phase: 8192 Re/Im pair-entries (A: 4096, B: 4096), 32 per thread
  for (int it = 0; it < 32; ++it) {
    const int e    = threadIdx.x + it * 256;
    const int k0   = e & 3;
    const int rp   = (e >> 2) & 7;      // row-pair within tile
    const int kt   = (e >> 5) & 31;     // k-chunk of 4
    const int tile = (e >> 10) & 3;     // m-tile / n-tile
    const bool isA = e < 4096;
    const int  i   = ks * KC + kt * 4 + k0;   // particle index
    float v0 = 0.f, v1 = 0.f;
    if (i < N) {
      const float x = coords[3 * i + 0];
      const float y = coords[3 * i + 1];
      const float z = coords[3 * i + 2];
      if (isA) {
        const int L = mtg * 32 + tile * 8 + rp;   // 0..319 (>=313 junk, unread)
        int h, k; line_hk(L, &h, &k);
        const float a = (x * C[0][0] + y * C[0][1] + z * C[0][2]) * invdet;
        const float b = (x * C[1][0] + y * C[1][1] + z * C[1][2]) * invdet;
        float t = fmaf((float)h, a, (float)k * b);       // revolutions
        float tf; asm("v_fract_f32 %0, %1" : "=v"(tf) : "v"(t));
        float s0, c0;
        asm("v_sin_f32 %0, %1" : "=v"(s0) : "v"(tf));
        asm("v_cos_f32 %0, %1" : "=v"(c0) : "v"(tf));
        const float qq = q[i];
        v0 = qq * c0; v1 = qq * s0;                      // Pr, Pi
      } else {
        const int ls = tile * 8 + rp;                    // 0..31 (>=25 junk, unread)
        const int l  = ls - KMAX;
        const float c = (x * C[2][0] + y * C[2][1] + z * C[2][2]) * invdet;
        float t = (float)l * c;
        float tf; asm("v_fract_f32 %0, %1" : "=v"(tf) : "v"(t));
        float s0, c0;
        asm("v_sin_f32 %0, %1" : "=v"(s0) : "v"(tf));
        asm("v_cos_f32 %0, %1" : "=v"(c0) : "v"(tf));
        v0 = c0; v1 = s0;                                // Rr, Ri
      }
    }
    if (isA) {
      Al[tile][kt][2 * rp + 0][k0] = (_Float16)v0;
      Al[tile][kt][2 * rp + 1][k0] = (_Float16)v1;
    } else {
      Bl[tile][kt][2 * rp + 0][k0] = (_Float16)v0;
      Bl[tile][kt][2 * rp + 1][k0] = (_Float16)v1;
    }
  }
  __syncthreads();

  // ---- MFMA phase: wave w owns m-tile w (16 rows x 64 cols), K = 128
  const int w    = threadIdx.x >> 6;
  const int lane = threadIdx.x & 63;
  const int r = lane & 15, g = lane >> 4;

  f32x4 acc0 = {0.f,0.f,0.f,0.f}, acc1 = {0.f,0.f,0.f,0.f};
  f32x4 acc2 = {0.f,0.f,0.f,0.f}, acc3 = {0.f,0.f,0.f,0.f};
#pragma unroll
  for (int s = 0; s < 4; ++s) {                          // 4 K-steps of 32
    union { half4 h4[2]; half8 h8; } ua;
    ua.h4[0] = *(const half4*)&Al[w][s * 8 + g][r][0];
    ua.h4[1] = *(const half4*)&Al[w][s * 8 + 4 + g][r][0];
    union { half4 h4[2]; half8 h8; } ub;
    ub.h4[0] = *(const half4*)&Bl[0][s * 8 + g][r][0];
    ub.h4[1] = *(const half4*)&Bl[0][s * 8 + 4 + g][r][0];
    acc0 = __builtin_amdgcn_mfma_f32_16x16x32_f16(ua.h8, ub.h8, acc0, 0, 0, 0);
    ub.h4[0] = *(const half4*)&Bl[1][s * 8 + g][r][0];
    ub.h4[1] = *(const half4*)&Bl[1][s * 8 + 4 + g][r][0];
    acc1 = __builtin_amdgcn_mfma_f32_16x16x32_f16(ua.h8, ub.h8, acc1, 0, 0, 0);
    ub.h4[0] = *(const half4*)&Bl[2][s * 8 + g][r][0];
    ub.h4[1] = *(const half4*)&Bl[2][s * 8 + 4 + g][r][0];
    acc2 = __builtin_amdgcn_mfma_f32_16x16x32_f16(ua.h8, ub.h8, acc2, 0, 0, 0);
    ub.h4[0] = *(const half4*)&Bl[3][s * 8 + g][r][0];
    ub.h4[1] = *(const half4*)&Bl[3][s * 8 + 4 + g][r][0];
    acc3 = __builtin_amdgcn_mfma_f32_16x16x32_f16(ua.h8, ub.h8, acc3, 0, 0, 0);
  }

  // C layout: col = lane&15, row = (lane>>4)*4 + reg  (HW-verified)
  float* base = Cp + ((size_t)ks * MROWS + mtg * 64 + w * 16) * NCOLS;
#pragma unroll
  for (int j = 0; j < 4; ++j) {
    base[(size_t)(g * 4 + j) * NCOLS +  0 + r] = acc0[j];
    base[(size_t)(g * 4 + j) * NCOLS + 16 + r] = acc1[j];
    base[(size_t)(g * 4 + j) * NCOLS + 32 + r] = acc2[j];
    base[(size_t)(g * 4 + j) * NCOLS + 48 + r] = acc3[j];
  }
}

// Per k-vec: sum split-K, combine Re/Im-interleaved 2x2 block, weight by fac.
__global__ __launch_bounds__(256) void stage2(
    const float* __restrict__ Cp, const float* __restrict__ box,
    float* __restrict__ out)
{
  __shared__ float red[256];
  const int idx = blockIdx.x * 256 + threadIdx.x;
  float e = 0.f;
  if (idx < NKV) {
    const int L  = idx / NL25;
    const int ls = idx % NL25;
    const int l  = ls - KMAX;
    int h, k; line_hk(L, &h, &k);
    if (!(h == 0 && k == 0 && l <= 0)) {   // mask non-half-space entries
      float Sre = 0.f, Sim = 0.f;
      for (int s = 0; s < NKS; ++s) {
        const float* c0 = Cp + ((size_t)s * MROWS + 2 * L) * NCOLS;
        const float prr = c0[2 * ls + 0];            // Pr.Rr
        const float pri = c0[2 * ls + 1];            // Pr.Ri
        const float pir = c0[NCOLS + 2 * ls + 0];    // Pi.Rr
        const float pii = c0[NCOLS + 2 * ls + 1];    // Pi.Ri
        Sre += prr - pii;
        Sim += pri + pir;
      }
      float C[3][3], det;
      cofactors(box, C, &det);
      const float invdet = 1.0f / det;
      const float hf = (float)h, kf = (float)k, lf = (float)l;
      const float kx = (hf * C[0][0] + kf * C[1][0] + lf * C[2][0]) * invdet;
      const float ky = (hf * C[0][1] + kf * C[1][1] + lf * C[2][1]) * invdet;
      const float kz = (hf * C[0][2] + kf * C[1][2] + lf * C[2][2]) * invdet;
      const float k2 = TWO_PI_ * TWO_PI_ * (kx * kx + ky * ky + kz * kz);
      const float fac = __expf(-k2 / (4.0f * ALPHA_ * ALPHA_)) / k2;
      e = fac * fmaf(Sre, Sre, Sim * Sim);
    }
  }
  red[threadIdx.x] = e;
  __syncthreads();
  for (int s = 128; s > 0; s >>= 1) {
    if (threadIdx.x < s) red[threadIdx.x] += red[threadIdx.x + s];
    __syncthreads();
  }
  if (threadIdx.x == 0) {
    float C[3][3], det;
    cofactors(box, C, &det);
    // E = (2*pi/V)*full_sum = (4*pi/V)*half_sum
    const float scale = (4.0f * 3.14159265358979323846f) / fabsf(det);
    atomicAdd(out, scale * red[0]);
  }
}

extern "C" void kernel_launch(void* const* d_in, const int* in_sizes, int n_in,
                              void* d_out, int out_size, void* d_ws, size_t ws_size,
                              hipStream_t stream) {
  const float* coords = (const float*)d_in[0];
  const float* box    = (const float*)d_in[1];
  const float* q      = (const float*)d_in[2];
  float* out = (float*)d_out;
  const int N = in_sizes[2];

  // ws: Cp = NKS*640*64 f32 = 5,242,880 B
  float* Cp = (float*)d_ws;

  hipLaunchKernelGGL(build_gemm, dim3(10, NKS), dim3(256), 0, stream,
                     coords, box, q, N, Cp, out);
  hipLaunchKernelGGL(stage2, dim3(S2_BLOCKS), dim3(256), 0, stream,
                     Cp, box, out);
}